// Round 1
// baseline (398.245 us; speedup 1.0000x reference)
//
#include <hip/hip_runtime.h>
#include <hip/hip_bf16.h>

// VeRA layer: out = SCALE * d_B[o] * sum_r B[o,r] * d_A[r] * sum_i x[m,i]*A[r,i]
// Factored: GEMM1 t = x @ (d_A*A)^T  (M=8192,N=256,K=4096)
//           GEMM2 out = SCALE*d_B * (t @ B^T)  (M=8192,N=4096,K=256)
// bf16 MFMA (16x16x32), fp32 accumulate. Threshold is 2% of max -> bf16 OK.

#define SCALE_F 0.125f
#define M_TOT 8192
#define K_IN 4096
#define RANK 256
#define N_OUT 4096

typedef __bf16 bf16_t;
typedef __bf16 bf16x8 __attribute__((ext_vector_type(8)));
typedef __bf16 bf16x4 __attribute__((ext_vector_type(4)));
typedef float f32x4 __attribute__((ext_vector_type(4)));

// ---- convert A (fold d_A) and B to bf16 ----
__global__ __launch_bounds__(256) void conv_A(const float* __restrict__ A,
                                              const float* __restrict__ dA,
                                              bf16_t* __restrict__ Ab) {
    int idx = blockIdx.x * 256 + threadIdx.x;          // one float4 per thread
    float4 v = ((const float4*)A)[idx];
    float s = dA[idx >> 10];                           // 4096 elems/row = 1024 float4
    bf16x4 o;
    o.x = (bf16_t)(v.x * s); o.y = (bf16_t)(v.y * s);
    o.z = (bf16_t)(v.z * s); o.w = (bf16_t)(v.w * s);
    ((bf16x4*)Ab)[idx] = o;
}

__global__ __launch_bounds__(256) void conv_B(const float* __restrict__ B,
                                              bf16_t* __restrict__ Bb) {
    int idx = blockIdx.x * 256 + threadIdx.x;
    float4 v = ((const float4*)B)[idx];
    bf16x4 o;
    o.x = (bf16_t)v.x; o.y = (bf16_t)v.y; o.z = (bf16_t)v.z; o.w = (bf16_t)v.w;
    ((bf16x4*)Bb)[idx] = o;
}

// ---- GEMM1: t[8192][256] = x(fp32) @ Ab^T ----
// BM=64, BN=64, BK=64. 256 thr = 4 waves (2x2). Wave tile 32x32 (WM=2,WN=2).
// grid (128, 4) = 512 blocks -> 2 blocks/CU.
__global__ __launch_bounds__(256) void gemm1(const float* __restrict__ x,
                                             const bf16_t* __restrict__ Ab,
                                             bf16_t* __restrict__ t) {
    __shared__ bf16_t sX[64 * 64];
    __shared__ bf16_t sA[64 * 64];
    const int tid = threadIdx.x;
    const int lane = tid & 63, wave = tid >> 6;
    const int wm = wave >> 1, wn = wave & 1;
    const int l15 = lane & 15, quad = lane >> 4;
    const int bm = blockIdx.x * 64;
    const int bn = blockIdx.y * 64;

    f32x4 acc[2][2];
    const f32x4 zero = {0.f, 0.f, 0.f, 0.f};
    for (int i = 0; i < 2; i++)
        for (int j = 0; j < 2; j++) acc[i][j] = zero;

    for (int kt = 0; kt < K_IN; kt += 64) {
        // stage x tile 64x64 fp32 -> bf16 LDS (2 chunks of 8 elems/thread)
        #pragma unroll
        for (int c = 0; c < 2; c++) {
            int f = (c * 256 + tid) * 8;
            int m = f >> 6, k = f & 63;
            const float4* g = (const float4*)&x[(size_t)(bm + m) * K_IN + kt + k];
            float4 v0 = g[0], v1 = g[1];
            bf16x8 o;
            o[0] = (bf16_t)v0.x; o[1] = (bf16_t)v0.y;
            o[2] = (bf16_t)v0.z; o[3] = (bf16_t)v0.w;
            o[4] = (bf16_t)v1.x; o[5] = (bf16_t)v1.y;
            o[6] = (bf16_t)v1.z; o[7] = (bf16_t)v1.w;
            *(bf16x8*)&sX[f] = o;
        }
        // stage Ab tile 64x64 bf16 (2 chunks)
        #pragma unroll
        for (int c = 0; c < 2; c++) {
            int f = (c * 256 + tid) * 8;
            int n = f >> 6, k = f & 63;
            int4 v = *(const int4*)&Ab[(size_t)(bn + n) * K_IN + kt + k];
            *(int4*)&sA[f] = v;
        }
        __syncthreads();
        #pragma unroll
        for (int ks = 0; ks < 2; ks++) {
            bf16x8 af[2], bfr[2];
            #pragma unroll
            for (int i = 0; i < 2; i++)
                af[i] = *(const bf16x8*)&sX[(wm * 32 + i * 16 + l15) * 64 + ks * 32 + quad * 8];
            #pragma unroll
            for (int j = 0; j < 2; j++)
                bfr[j] = *(const bf16x8*)&sA[(wn * 32 + j * 16 + l15) * 64 + ks * 32 + quad * 8];
            #pragma unroll
            for (int i = 0; i < 2; i++)
                #pragma unroll
                for (int j = 0; j < 2; j++)
                    acc[i][j] = __builtin_amdgcn_mfma_f32_16x16x32_bf16(af[i], bfr[j], acc[i][j], 0, 0, 0);
        }
        __syncthreads();
    }
    // epilogue: t bf16, C/D layout col=lane&15, row=quad*4+r  [verified m89/m91]
    #pragma unroll
    for (int i = 0; i < 2; i++) {
        #pragma unroll
        for (int j = 0; j < 2; j++) {
            int col = bn + wn * 32 + j * 16 + l15;
            #pragma unroll
            for (int r = 0; r < 4; r++) {
                int row = bm + wm * 32 + i * 16 + quad * 4 + r;
                t[(size_t)row * RANK + col] = (bf16_t)acc[i][j][r];
            }
        }
    }
}

// ---- GEMM2: out[8192][4096] = SCALE * dB[o] * (t @ Bb^T) ----
// BM=128, BN=128, BK=64 (4 k-iters). Wave tile 64x64 (WM=4,WN=4). grid (64,32)=2048 blocks.
__global__ __launch_bounds__(256) void gemm2(const bf16_t* __restrict__ t,
                                             const bf16_t* __restrict__ Bb,
                                             const float* __restrict__ dB,
                                             float* __restrict__ out) {
    __shared__ bf16_t sT[128 * 64];
    __shared__ bf16_t sB[128 * 64];
    const int tid = threadIdx.x;
    const int lane = tid & 63, wave = tid >> 6;
    const int wm = wave >> 1, wn = wave & 1;
    const int l15 = lane & 15, quad = lane >> 4;
    const int bm = blockIdx.x * 128;
    const int bn = blockIdx.y * 128;

    f32x4 acc[4][4];
    const f32x4 zero = {0.f, 0.f, 0.f, 0.f};
    for (int i = 0; i < 4; i++)
        for (int j = 0; j < 4; j++) acc[i][j] = zero;

    for (int kt = 0; kt < RANK; kt += 64) {
        #pragma unroll
        for (int c = 0; c < 4; c++) {
            int f = (c * 256 + tid) * 8;
            int m = f >> 6, k = f & 63;
            int4 v = *(const int4*)&t[(size_t)(bm + m) * RANK + kt + k];
            *(int4*)&sT[f] = v;
        }
        #pragma unroll
        for (int c = 0; c < 4; c++) {
            int f = (c * 256 + tid) * 8;
            int n = f >> 6, k = f & 63;
            int4 v = *(const int4*)&Bb[(size_t)(bn + n) * RANK + kt + k];
            *(int4*)&sB[f] = v;
        }
        __syncthreads();
        #pragma unroll
        for (int ks = 0; ks < 2; ks++) {
            bf16x8 af[4], bfr[4];
            #pragma unroll
            for (int i = 0; i < 4; i++)
                af[i] = *(const bf16x8*)&sT[(wm * 64 + i * 16 + l15) * 64 + ks * 32 + quad * 8];
            #pragma unroll
            for (int j = 0; j < 4; j++)
                bfr[j] = *(const bf16x8*)&sB[(wn * 64 + j * 16 + l15) * 64 + ks * 32 + quad * 8];
            #pragma unroll
            for (int i = 0; i < 4; i++)
                #pragma unroll
                for (int j = 0; j < 4; j++)
                    acc[i][j] = __builtin_amdgcn_mfma_f32_16x16x32_bf16(af[i], bfr[j], acc[i][j], 0, 0, 0);
        }
        __syncthreads();
    }
    // epilogue: out fp32, fold SCALE*dB
    #pragma unroll
    for (int j = 0; j < 4; j++) {
        int col = bn + wn * 64 + j * 16 + l15;
        float db = dB[col] * SCALE_F;
        #pragma unroll
        for (int i = 0; i < 4; i++) {
            #pragma unroll
            for (int r = 0; r < 4; r++) {
                int row = bm + wm * 64 + i * 16 + quad * 4 + r;
                out[(size_t)row * N_OUT + col] = db * acc[i][j][r];
            }
        }
    }
}

extern "C" void kernel_launch(void* const* d_in, const int* in_sizes, int n_in,
                              void* d_out, int out_size, void* d_ws, size_t ws_size,
                              hipStream_t stream) {
    const float* x  = (const float*)d_in[0];   // (4,2048,4096) = 8192x4096
    const float* A  = (const float*)d_in[1];   // (256,4096)
    const float* B  = (const float*)d_in[2];   // (4096,256)
    const float* dA = (const float*)d_in[3];   // (256,)
    const float* dB = (const float*)d_in[4];   // (4096,)
    float* out = (float*)d_out;                // 8192x4096 fp32

    char* ws = (char*)d_ws;
    bf16_t* Ab = (bf16_t*)ws;                          // 256*4096*2  = 2 MB
    bf16_t* Bb = (bf16_t*)(ws + (1u << 21));           // 4096*256*2  = 2 MB
    bf16_t* tt = (bf16_t*)(ws + (1u << 22));           // 8192*256*2  = 4 MB

    conv_A<<<1024, 256, 0, stream>>>(A, dA, Ab);       // 1048576/4 float4s
    conv_B<<<1024, 256, 0, stream>>>(B, Bb);
    gemm1<<<dim3(128, 4), 256, 0, stream>>>(x, Ab, tt);
    gemm2<<<dim3(64, 32), 256, 0, stream>>>(tt, Bb, dB, out);
}

// Round 2
// 314.302 us; speedup vs baseline: 1.2671x; 1.2671x over previous
//
#include <hip/hip_runtime.h>
#include <hip/hip_bf16.h>

// VeRA: out = SCALE * d_B[o] * ((x @ (d_A*A)^T) @ B^T)
// GEMM1 (split-K=4): part[s] = x @ Ab^T over K-chunk  (M=8192,N=256,K=1024 each)
// reduce: t = bf16(sum_s part[s])
// GEMM2: out = SCALE*d_B * (t @ Bb^T)  (M=8192,N=4096,K=256)

#define SCALE_F 0.125f
#define M_TOT 8192
#define K_IN 4096
#define RANK 256
#define N_OUT 4096
#define S_SPLIT 4
#define KC 1024   // K_IN / S_SPLIT

typedef __bf16 bf16_t;
typedef __bf16 bf16x8 __attribute__((ext_vector_type(8)));
typedef __bf16 bf16x4 __attribute__((ext_vector_type(4)));
typedef float f32x4 __attribute__((ext_vector_type(4)));

typedef __attribute__((address_space(3))) unsigned int lds_u32_t;
typedef const __attribute__((address_space(1))) unsigned int glob_u32_t;

__device__ __forceinline__ void async16(const void* g, void* l) {
    __builtin_amdgcn_global_load_lds((glob_u32_t*)g, (lds_u32_t*)l, 16, 0, 0);
}

// ---- convert A (fold d_A) and B to bf16 ----
__global__ __launch_bounds__(256) void conv_A(const float* __restrict__ A,
                                              const float* __restrict__ dA,
                                              bf16_t* __restrict__ Ab) {
    int idx = blockIdx.x * 256 + threadIdx.x;
    float4 v = ((const float4*)A)[idx];
    float s = dA[idx >> 10];
    bf16x4 o;
    o.x = (bf16_t)(v.x * s); o.y = (bf16_t)(v.y * s);
    o.z = (bf16_t)(v.z * s); o.w = (bf16_t)(v.w * s);
    ((bf16x4*)Ab)[idx] = o;
}

__global__ __launch_bounds__(256) void conv_B(const float* __restrict__ B,
                                              bf16_t* __restrict__ Bb) {
    int idx = blockIdx.x * 256 + threadIdx.x;
    float4 v = ((const float4*)B)[idx];
    bf16x4 o;
    o.x = (bf16_t)v.x; o.y = (bf16_t)v.y; o.z = (bf16_t)v.z; o.w = (bf16_t)v.w;
    ((bf16x4*)Bb)[idx] = o;
}

// ---- GEMM1: part[z][8192][256] = x(fp32) @ Ab^T over K-chunk z ----
// BM=64, BN=128, BK=64. grid (128, 2, 4) = 1024 blocks. 4 waves: 2x2, wave tile 32x64.
// x staged as fp32 in LDS via global_load_lds; cvt to bf16 at fragment read.
__global__ __launch_bounds__(256) void gemm1(const float* __restrict__ x,
                                             const bf16_t* __restrict__ Ab,
                                             bf16_t* __restrict__ part) {
    __shared__ float  sX[64 * 64];    // 16 KB
    __shared__ bf16_t sA[128 * 64];   // 16 KB
    const int tid = threadIdx.x;
    const int lane = tid & 63, wave = tid >> 6;
    const int wm = wave >> 1, wn = wave & 1;
    const int l15 = lane & 15, quad = lane >> 4;
    const int bm = blockIdx.x * 64;
    const int bn = blockIdx.y * 128;
    const int k0 = blockIdx.z * KC;

    f32x4 acc[2][4];
    const f32x4 zero = {0.f, 0.f, 0.f, 0.f};
    #pragma unroll
    for (int i = 0; i < 2; i++)
        #pragma unroll
        for (int j = 0; j < 4; j++) acc[i][j] = zero;

    for (int kt = 0; kt < KC; kt += 64) {
        // sX: 64 rows x 64 fp32; 16B/lane, 4 passes
        #pragma unroll
        for (int c = 0; c < 4; c++) {
            int idx = c * 256 + tid;
            int m = idx >> 4, kc = (idx & 15) * 4;
            async16(&x[(size_t)(bm + m) * K_IN + k0 + kt + kc], &sX[idx * 4]);
        }
        // sA: 128 rows x 64 bf16; 16B/lane, 4 passes
        #pragma unroll
        for (int c = 0; c < 4; c++) {
            int idx = c * 256 + tid;
            int n = idx >> 3, kc = (idx & 7) * 8;
            async16(&Ab[(size_t)(bn + n) * K_IN + k0 + kt + kc], &sA[idx * 8]);
        }
        __syncthreads();
        #pragma unroll
        for (int ks = 0; ks < 2; ks++) {
            bf16x8 af[2], bfr[4];
            #pragma unroll
            for (int i = 0; i < 2; i++) {
                const float* p = &sX[(wm * 32 + i * 16 + l15) * 64 + ks * 32 + quad * 8];
                f32x4 v0 = *(const f32x4*)p;
                f32x4 v1 = *(const f32x4*)(p + 4);
                bf16x8 t;
                t[0] = (bf16_t)v0[0]; t[1] = (bf16_t)v0[1];
                t[2] = (bf16_t)v0[2]; t[3] = (bf16_t)v0[3];
                t[4] = (bf16_t)v1[0]; t[5] = (bf16_t)v1[1];
                t[6] = (bf16_t)v1[2]; t[7] = (bf16_t)v1[3];
                af[i] = t;
            }
            #pragma unroll
            for (int j = 0; j < 4; j++)
                bfr[j] = *(const bf16x8*)&sA[(wn * 64 + j * 16 + l15) * 64 + ks * 32 + quad * 8];
            #pragma unroll
            for (int i = 0; i < 2; i++)
                #pragma unroll
                for (int j = 0; j < 4; j++)
                    acc[i][j] = __builtin_amdgcn_mfma_f32_16x16x32_bf16(af[i], bfr[j], acc[i][j], 0, 0, 0);
        }
        __syncthreads();
    }
    bf16_t* p = part + (size_t)blockIdx.z * M_TOT * RANK;
    #pragma unroll
    for (int i = 0; i < 2; i++) {
        #pragma unroll
        for (int j = 0; j < 4; j++) {
            int col = bn + wn * 64 + j * 16 + l15;
            #pragma unroll
            for (int r = 0; r < 4; r++) {
                int row = bm + wm * 32 + i * 16 + quad * 4 + r;
                p[(size_t)row * RANK + col] = (bf16_t)acc[i][j][r];
            }
        }
    }
}

// ---- reduce: t = bf16(sum_z part[z]) ----
__global__ __launch_bounds__(256) void reduce_t(const bf16_t* __restrict__ part,
                                                bf16_t* __restrict__ t) {
    int i = (blockIdx.x * 256 + threadIdx.x) * 8;
    float s[8] = {0.f, 0.f, 0.f, 0.f, 0.f, 0.f, 0.f, 0.f};
    #pragma unroll
    for (int z = 0; z < S_SPLIT; z++) {
        bf16x8 v = *(const bf16x8*)&part[(size_t)z * M_TOT * RANK + i];
        #pragma unroll
        for (int e = 0; e < 8; e++) s[e] += (float)v[e];
    }
    bf16x8 o;
    #pragma unroll
    for (int e = 0; e < 8; e++) o[e] = (bf16_t)s[e];
    *(bf16x8*)&t[i] = o;
}

// ---- GEMM2: out[8192][4096] = SCALE*dB * (t @ Bb^T) ----
// BM=128, BN=64, BK=64 (4 iters). grid (64,64)=4096 blocks. 4 waves: 2x2, wave tile 64x32.
__global__ __launch_bounds__(256) void gemm2(const bf16_t* __restrict__ t,
                                             const bf16_t* __restrict__ Bb,
                                             const float* __restrict__ dB,
                                             float* __restrict__ out) {
    __shared__ bf16_t sT[128 * 64];   // 16 KB
    __shared__ bf16_t sB[64 * 64];    // 8 KB
    const int tid = threadIdx.x;
    const int lane = tid & 63, wave = tid >> 6;
    const int wm = wave >> 1, wn = wave & 1;
    const int l15 = lane & 15, quad = lane >> 4;
    const int bm = blockIdx.x * 128;
    const int bn = blockIdx.y * 64;

    f32x4 acc[4][2];
    const f32x4 zero = {0.f, 0.f, 0.f, 0.f};
    #pragma unroll
    for (int i = 0; i < 4; i++)
        #pragma unroll
        for (int j = 0; j < 2; j++) acc[i][j] = zero;

    for (int kt = 0; kt < RANK; kt += 64) {
        #pragma unroll
        for (int c = 0; c < 4; c++) {
            int idx = c * 256 + tid;
            int m = idx >> 3, kc = (idx & 7) * 8;
            async16(&t[(size_t)(bm + m) * RANK + kt + kc], &sT[idx * 8]);
        }
        #pragma unroll
        for (int c = 0; c < 2; c++) {
            int idx = c * 256 + tid;
            int n = idx >> 3, kc = (idx & 7) * 8;
            async16(&Bb[(size_t)(bn + n) * RANK + kt + kc], &sB[idx * 8]);
        }
        __syncthreads();
        #pragma unroll
        for (int ks = 0; ks < 2; ks++) {
            bf16x8 af[4], bfr[2];
            #pragma unroll
            for (int i = 0; i < 4; i++)
                af[i] = *(const bf16x8*)&sT[(wm * 64 + i * 16 + l15) * 64 + ks * 32 + quad * 8];
            #pragma unroll
            for (int j = 0; j < 2; j++)
                bfr[j] = *(const bf16x8*)&sB[(wn * 32 + j * 16 + l15) * 64 + ks * 32 + quad * 8];
            #pragma unroll
            for (int i = 0; i < 4; i++)
                #pragma unroll
                for (int j = 0; j < 2; j++)
                    acc[i][j] = __builtin_amdgcn_mfma_f32_16x16x32_bf16(af[i], bfr[j], acc[i][j], 0, 0, 0);
        }
        __syncthreads();
    }
    #pragma unroll
    for (int j = 0; j < 2; j++) {
        int col = bn + wn * 32 + j * 16 + l15;
        float db = dB[col] * SCALE_F;
        #pragma unroll
        for (int i = 0; i < 4; i++) {
            #pragma unroll
            for (int r = 0; r < 4; r++) {
                int row = bm + wm * 64 + i * 16 + quad * 4 + r;
                out[(size_t)row * N_OUT + col] = db * acc[i][j][r];
            }
        }
    }
}

extern "C" void kernel_launch(void* const* d_in, const int* in_sizes, int n_in,
                              void* d_out, int out_size, void* d_ws, size_t ws_size,
                              hipStream_t stream) {
    const float* x  = (const float*)d_in[0];
    const float* A  = (const float*)d_in[1];
    const float* B  = (const float*)d_in[2];
    const float* dA = (const float*)d_in[3];
    const float* dB = (const float*)d_in[4];
    float* out = (float*)d_out;

    char* ws = (char*)d_ws;
    bf16_t* Ab   = (bf16_t*)ws;                       // 2 MB
    bf16_t* Bb   = (bf16_t*)(ws + (1u << 21));        // 2 MB
    bf16_t* tt   = (bf16_t*)(ws + (1u << 22));        // 4 MB
    bf16_t* part = (bf16_t*)(ws + (1u << 23));        // 4 * 4 MB = 16 MB

    conv_A<<<1024, 256, 0, stream>>>(A, dA, Ab);
    conv_B<<<1024, 256, 0, stream>>>(B, Bb);
    gemm1<<<dim3(128, 2, S_SPLIT), 256, 0, stream>>>(x, Ab, part);
    reduce_t<<<1024, 256, 0, stream>>>(part, tt);
    gemm2<<<dim3(64, 64), 256, 0, stream>>>(tt, Bb, dB, out);
}